// Round 7
// baseline (150.815 us; speedup 1.0000x reference)
//
#include <hip/hip_runtime.h>
#include <cstddef>

// Problem constants (match reference)
constexpr int Bn   = 2048;
constexpr int Dn   = 512;
constexpr int NCLS = 100;
constexpr unsigned WWIN = 32768;  // window width in key units (ulp = 2^-20 at |L|~14.3)
constexpr int NH = 32768;         // 1-ulp histogram bins across the window (R17)

// VERIFIED INVARIANT (R4): reference adc[i][j] = fl32( single fma chain k=0..511 ) / 0.07f,
// strict ascending k, one fused fma per step, single fp32 accumulator. DO NOT reassociate,
// split K, or use MFMA — masks flip at sub-ulp rank gaps.
// adc bitwise symmetric -> lower triangle + mirror. Row max == diag == fl32(chain(F[i]·F[i]))/0.07f.
// STABILITY (R9-R11 bisect): 528-block/256-thread gemm structure is HW-proven; single-wave
// 2080-block variant killed containers twice. Do not revisit.
// R14 LESSON (measured): microtile LDS:VALU ratio = 6(m+n)/mn; 4x4 is the feasible optimum.
// R16 LESSON (measured): agent-scope scalar loads serialize (~700cyc each); never bulk-scan.
// R17 LESSON (measured): 1-ulp hist killed the cand-scan tail. Plain first-touch loads after
// ticket are coherent for atomic-written lines (proven R17/R18/R19 passes).
// R19 LESSON (measured): BK=32 bought only ~3us -> gemm floor = LDS pipe (~42us dense) +
// straggler round (~20us, 528>512 residency) + tail (~5us). Both phases run at the same
// ~21us/tile LDS-limited rate. gemm 71us is near its structural floor at fixed semantics.
// R20 ANALYSIS: budget says final_k ~ 60-68us (total - gemm - rowdot - boundaries), hidden
// just under gemm in top-5. Cause: mask planes at out+1 make every 16B store 4-mod-16 ->
// 4 scalar dwords each (64 store-instrs/wave-row, partial lines) + only 1 block/CU.
// R20 FIX: shift-store realignment — lane L stores {prev.w, this.xyz} at plane[i*Bn+jb-1]
// (byte addr 4*(2048i+jb) == 0 mod 16 -> TRUE dwordx4); .w travels via __shfl_up + carry.
// Compute/reduction partitions untouched -> masks AND loss bitwise identical. Grid 256->512.
// The float4 casts in final_k are to PROVEN-aligned addresses (see derivation above); the
// old "never cast float4*" rule applied to the 4-mod-16 raw addresses only.

struct Ctl {
  unsigned above;      // 0:  # negatives with key >= window hi (device atomics only)
  unsigned candCount;  // 4:  unused (layout kept)
  unsigned singles;    // 8:  final_k master ticket (zeroed by rowdot)
  unsigned done;       // 12: gemm master ticket (zeroed by rowdot)
  float    thrF;       // 16
  unsigned pad1;       // 20
  double   lossSum;    // 24..31 (unused; layout kept)
  unsigned hist[NH];   // 32: 1-ulp bins over window (device atomics only)
  unsigned done8[128]; // gemm slice tickets, stride 16 (64B apart)
  unsigned sing8[128]; // final_k slice tickets, stride 16
};
static_assert(offsetof(Ctl, hist) == 32, "zero loop covers head + hist + slices");

// Monotone fp32 <-> uint32 order keys
__device__ inline unsigned key_of(float L) {
  unsigned u = __float_as_uint(L);
  return (u & 0x80000000u) ? ~u : (u | 0x80000000u);
}
__device__ inline float key_to_float(unsigned key) {
  unsigned u = (key & 0x80000000u) ? (key ^ 0x80000000u) : ~key;
  return __uint_as_float(u);
}
// Window: centered at -1/0.07 (negative-pair median), +-16384 ulps (~28 sigma of median est.)
__device__ inline unsigned wlo_key() {
  const float c0 = -1.0f / 0.07f;
  return key_of(c0) - (WWIN / 2);
}
// Agent-scope write-through stores (to coherent point; reader uses plain first-touch loads)
__device__ inline void agent_store_f64(double* p, double v) {
  __hip_atomic_store(p, v, __ATOMIC_RELAXED, __HIP_MEMORY_SCOPE_AGENT);
}
__device__ inline void agent_store_u32(unsigned* p, unsigned v) {
  __hip_atomic_store(p, v, __ATOMIC_RELAXED, __HIP_MEMORY_SCOPE_AGENT);
}

// ------- per-row self-dot: rm[i] bitwise == adc[i][i]; fused Ctl zeroing. 32 blocks x 64 -------
__global__ __launch_bounds__(64) void rowdot_k(const float* __restrict__ F,
                                               float* __restrict__ rm, Ctl* c) {
  const int i = blockIdx.x * 64 + threadIdx.x;
  const float4* p = (const float4*)(F + (size_t)i * Dn);
  float acc = 0.0f;
#pragma unroll 16
  for (int q = 0; q < 128; ++q) {
    const float4 f = p[q];
    acc = __builtin_fmaf(f.x, f.x, acc);
    acc = __builtin_fmaf(f.y, f.y, acc);
    acc = __builtin_fmaf(f.z, f.z, acc);
    acc = __builtin_fmaf(f.w, f.w, acc);   // strict ascending-k chain, same as gemm
  }
  rm[i] = acc / 0.07f;                     // IEEE fp32 div: bitwise == adc[i][i]
  // fused Ctl zeroing: head(8) + hist(NH) + done8(128) + sing8(128) dwords
  unsigned* cz = (unsigned*)c;
  for (int idx = i; idx < 8 + NH + 256; idx += 2048) cz[idx] = 0;
}

// -------- GEMM: lower-triangle 64x64 tiles, BK=32 dbuf, mirror + fused 1-ulp window hist --------
// + split-ticket last-block select tail (66/slice x 8 slices -> 8 masters -> 1 tail block).
__global__ __launch_bounds__(256) void gemm_adc(const float* __restrict__ F,
                                                const float* __restrict__ rm,
                                                const int* __restrict__ labels,
                                                float* __restrict__ adc, Ctl* c) {
  __shared__ float smem[8704];   // As dbuf [0,4352), Bs dbuf [4352,8704); reused: transpose, tail
  __shared__ int slabi[64], slabj[64];
  __shared__ float rmiA[64], rmjA[64];
  __shared__ unsigned abcnt;
  __shared__ unsigned amlast;
  const int t = threadIdx.x;
  int r = 0;
  { const int idx = blockIdx.x; while ((r + 1) * (r + 2) / 2 <= idx) ++r; }
  const int cc = blockIdx.x - r * (r + 1) / 2;
  const int i0 = r * 64, j0 = cc * 64;

  const int tx = t & 15, ty = t >> 4;        // 16x16 thread grid, 4x4 microtile
  const int lrow = t >> 2, lq = t & 3;       // loader: row 0..63, k-quad 0..3 (+16 for hi half)

  if (t < 64) {
    slabi[t] = labels[i0 + t]; rmiA[t] = rm[i0 + t];
    slabj[t] = labels[j0 + t]; rmjA[t] = rm[j0 + t];
  }
  if (t == 0) abcnt = 0;

  float acc[4][4] = {};
  const float* Ab = F + (size_t)(i0 + lrow) * Dn;
  const float* Bb = F + (size_t)(j0 + lrow) * Dn;
  float* As = smem;           // [buf*2176 + k*68 + row], k 0..31
  float* Bs = smem + 4352;

  float4 a0 = *(const float4*)(Ab + lq * 4);
  float4 a1 = *(const float4*)(Ab + lq * 4 + 16);
  float4 b0 = *(const float4*)(Bb + lq * 4);
  float4 b1 = *(const float4*)(Bb + lq * 4 + 16);
  {
    const int k0 = lq * 4;
    As[(k0 + 0) * 68 + lrow] = a0.x; As[(k0 + 1) * 68 + lrow] = a0.y;
    As[(k0 + 2) * 68 + lrow] = a0.z; As[(k0 + 3) * 68 + lrow] = a0.w;
    As[(k0 + 16) * 68 + lrow] = a1.x; As[(k0 + 17) * 68 + lrow] = a1.y;
    As[(k0 + 18) * 68 + lrow] = a1.z; As[(k0 + 19) * 68 + lrow] = a1.w;
    Bs[(k0 + 0) * 68 + lrow] = b0.x; Bs[(k0 + 1) * 68 + lrow] = b0.y;
    Bs[(k0 + 2) * 68 + lrow] = b0.z; Bs[(k0 + 3) * 68 + lrow] = b0.w;
    Bs[(k0 + 16) * 68 + lrow] = b1.x; Bs[(k0 + 17) * 68 + lrow] = b1.y;
    Bs[(k0 + 18) * 68 + lrow] = b1.z; Bs[(k0 + 19) * 68 + lrow] = b1.w;
  }
  __syncthreads();

  for (int ch = 0; ch < 16; ++ch) {
    const int cur = ch & 1, nxt = cur ^ 1;
    if (ch < 15) {
      const int kg = (ch + 1) * 32;
      a0 = *(const float4*)(Ab + kg + lq * 4);
      a1 = *(const float4*)(Ab + kg + lq * 4 + 16);
      b0 = *(const float4*)(Bb + kg + lq * 4);
      b1 = *(const float4*)(Bb + kg + lq * 4 + 16);
    }
    const float* Ac = As + cur * 2176;
    const float* Bc = Bs + cur * 2176;
#pragma unroll
    for (int k = 0; k < 32; ++k) {           // global k = ch*32 + k, strictly ascending
      const float4 av = *(const float4*)(Ac + k * 68 + ty * 4);
      const float4 bv = *(const float4*)(Bc + k * 68 + tx * 4);
      const float aa[4] = {av.x, av.y, av.z, av.w};
      const float bb[4] = {bv.x, bv.y, bv.z, bv.w};
#pragma unroll
      for (int m = 0; m < 4; ++m)
#pragma unroll
        for (int n = 0; n < 4; ++n)
          acc[m][n] = __builtin_fmaf(aa[m], bb[n], acc[m][n]);  // strict k-order chain
    }
    if (ch < 15) {
      const int k0 = lq * 4;
      float* An = As + nxt * 2176;
      float* Bm = Bs + nxt * 2176;
      An[(k0 + 0) * 68 + lrow] = a0.x; An[(k0 + 1) * 68 + lrow] = a0.y;
      An[(k0 + 2) * 68 + lrow] = a0.z; An[(k0 + 3) * 68 + lrow] = a0.w;
      An[(k0 + 16) * 68 + lrow] = a1.x; An[(k0 + 17) * 68 + lrow] = a1.y;
      An[(k0 + 18) * 68 + lrow] = a1.z; An[(k0 + 19) * 68 + lrow] = a1.w;
      Bm[(k0 + 0) * 68 + lrow] = b0.x; Bm[(k0 + 1) * 68 + lrow] = b0.y;
      Bm[(k0 + 2) * 68 + lrow] = b0.z; Bm[(k0 + 3) * 68 + lrow] = b0.w;
      Bm[(k0 + 16) * 68 + lrow] = b1.x; Bm[(k0 + 17) * 68 + lrow] = b1.y;
      Bm[(k0 + 18) * 68 + lrow] = b1.z; Bm[(k0 + 19) * 68 + lrow] = b1.w;
    }
    __syncthreads();
  }

  // epilogue: /0.07f, store own tile
  float v[4][4];
#pragma unroll
  for (int m = 0; m < 4; ++m) {
#pragma unroll
    for (int n = 0; n < 4; ++n) v[m][n] = acc[m][n] / 0.07f;   // IEEE fp32 div
    float4 q = {v[m][0], v[m][1], v[m][2], v[m][3]};
    *(float4*)&adc[(size_t)(i0 + ty * 4 + m) * Bn + j0 + tx * 4] = q;
  }
  if (r != cc) {
    // mirror via LDS transpose (bitwise-identical values)
    __syncthreads();               // block-uniform; k-loop LDS reads done
    float* T = smem;               // 64 x 68
#pragma unroll
    for (int m = 0; m < 4; ++m)
#pragma unroll
      for (int n = 0; n < 4; ++n)
        T[(tx * 4 + n) * 68 + (ty * 4 + m)] = v[m][n];
    __syncthreads();
#pragma unroll
    for (int e = 0; e < 4; ++e) {
      const int row2 = e * 16 + ty;  // mirror row = original col
      *(float4*)&adc[(size_t)(j0 + row2) * Bn + i0 + tx * 4] =
          *(const float4*)(T + row2 * 68 + tx * 4);
    }
  }

  // fused 1-ulp window histogram (own tile + mirror), values still in registers
  __syncthreads();
  const unsigned klo = wlo_key(), khi = klo + WWIN;
  unsigned myab = 0;
#pragma unroll
  for (int m = 0; m < 4; ++m) {
    const int gi = i0 + ty * 4 + m;
    const int li = slabi[ty * 4 + m];
    const float rmi = rmiA[ty * 4 + m];
#pragma unroll
    for (int n = 0; n < 4; ++n) {
      const int gj = j0 + tx * 4 + n;
      if (gi == gj || li == slabj[tx * 4 + n]) continue;
      const unsigned key = key_of(v[m][n] - rmi);   // exact fp32 sub
      if (key >= khi) ++myab;
      else if (key >= klo) atomicAdd(&c->hist[key - klo], 1u);
      if (r != cc) {
        const unsigned key2 = key_of(v[m][n] - rmjA[tx * 4 + n]);
        if (key2 >= khi) ++myab;
        else if (key2 >= klo) atomicAdd(&c->hist[key2 - klo], 1u);
      }
    }
  }
  if (myab) atomicAdd(&abcnt, myab);
  __syncthreads();
  if (t == 0 && abcnt) atomicAdd(&c->above, abcnt);

  // ------------- split-ticket select tail (66/slice x 8 -> 8 masters -> 1 tail) -------------
  __syncthreads();                 // barrier waitcnt drains this block's hist/above atomics
  if (t == 0) {
    const int sl = (int)(blockIdx.x & 7);
    unsigned am = 0u;
    if (atomicAdd(&c->done8[sl * 16], 1u) == 65u)
      am = (atomicAdd(&c->done, 1u) == 7u) ? 1u : 0u;
    amlast = am;
  }
  __syncthreads();
  if (!amlast) return;

  // LDS overlay (k-loop/transpose storage is dead here)
  unsigned* s_cnt  = (unsigned*)smem;          // [0,128)
  unsigned* s_tsum = (unsigned*)smem + 128;    // [128,384)
  unsigned* s_scan = (unsigned*)smem + 384;    // [384,640)
  if (t < 128) s_cnt[t] = 0;
  __syncthreads();
  for (int j = t; j < Bn; j += 256) atomicAdd(&s_cnt[labels[j]], 1u);
  __syncthreads();
  // parallel sum of cnt^2: tree-reduce over 256 slots (t >= NCLS contribute 0)
  s_scan[t] = (t < NCLS) ? s_cnt[t] * s_cnt[t] : 0u;
  __syncthreads();
#pragma unroll
  for (int off = 128; off > 0; off >>= 1) {
    if (t < off) s_scan[t] += s_scan[t + off];
    __syncthreads();
  }
  unsigned kk = (((unsigned)Bn * Bn) - s_scan[0]) >> 1;   // floor(0.5*n_neg), exact vs ref
  if (kk < 1u) kk = 1u;
  __syncthreads();                 // s_scan reuse below

  // pass 1: per-thread bin sums (plain vector loads; first touch -> coherent point)
  const uint4* hp = (const uint4*)c->hist;   // 8192 quads; thread t owns quads [t*32, t*32+32)
  unsigned s = 0;
#pragma unroll 8
  for (int bq = 0; bq < 32; ++bq) {
    const uint4 vq = hp[t * 32 + bq];
    s += vq.x + vq.y + vq.z + vq.w;
  }
  s_tsum[t] = s;
  s_scan[t] = s;
  __syncthreads();
  // Hillis-Steele inclusive SUFFIX scan: s_scan[t] = sum_{q>=t} tsum[q]
#pragma unroll
  for (int off = 1; off < 256; off <<= 1) {
    const unsigned add = (t + off < 256) ? s_scan[t + off] : 0u;
    __syncthreads();
    s_scan[t] += add;
    __syncthreads();
  }
  // exclusive suffix + above (identical semantics to R17's serial loop)
  const unsigned above = c->above;             // atomic-written; plain first touch coherent
  unsigned cum = above + s_scan[t] - s_tsum[t];
  // pass 2: descending crossing search (L2-warm reload); exactly one thread finds the bin
  int fbin = -1;
#pragma unroll 8
  for (int bq = 31; bq >= 0; --bq) {
    const uint4 vq = hp[t * 32 + bq];
    const unsigned hq[4] = {vq.x, vq.y, vq.z, vq.w};
#pragma unroll
    for (int u = 3; u >= 0; --u) {
      if (cum < kk && cum + hq[u] >= kk) fbin = t * 128 + bq * 4 + u;
      cum += hq[u];
    }
  }
  if (fbin >= 0) c->thrF = key_to_float(klo + (unsigned)fbin);  // plain store; boundary flushes
}

// ------- fused mask + loss: 512 blocks x 4 rows (1 row/wave), ALIGNED dwordx4 mask stores -------
// Shift-store realignment: lane L stores {prev_lane.w, this.xyz} at plane[i*Bn + jb - 1];
// byte address = 4*(2048*i + jb) == 0 mod 16 -> true float4 stores. The .w element travels
// right by one lane via __shfl_up; chunk boundary via lane-63 carry broadcast. Row head
// (j=0..2) and row tail (j=2047) are scalar edge stores. Per-thread compute and reduction
// partitions are UNCHANGED -> masks and loss bitwise identical to R19.
__global__ __launch_bounds__(256) void final_k(const float* __restrict__ adc,
                                               const int* __restrict__ labels,
                                               Ctl* c,
                                               float* __restrict__ out,
                                               double* __restrict__ lsum_g,
                                               unsigned* __restrict__ scnt_g) {
  __shared__ int slab[Bn];
  __shared__ double lsum[4];
  __shared__ unsigned sflag[4];
  __shared__ unsigned amlast;
  const int t = threadIdx.x;
  const int lane = t & 63, w = t >> 6;
#pragma unroll
  for (int e = 0; e < 2; ++e)                      // int4 slab staging, once per 4 rows
    ((int4*)slab)[t + 256 * e] = ((const int4*)labels)[t + 256 * e];
  __syncthreads();
  const float thr = c->thrF;
  float* __restrict__ ohnm = out + 1;
  float* __restrict__ ofin = out + 1 + (size_t)Bn * Bn;

  const int i = blockIdx.x * 4 + w;                // wave w owns one row
  const int li = slab[i];
  const float rm = adc[(size_t)i * Bn + i];        // diag == row max (bitwise)
  const float4* rowp = (const float4*)(adc + (size_t)i * Bn);
  const size_t rowb = (size_t)i * Bn;
  float se = 0.0f, sp = 0.0f;
  int pc = 0;
  float carry_h = 0.0f, carry_f = 0.0f;            // j = 256q-1 element, lane63 -> lane0
  float qh3 = 0.0f, qf3 = 0.0f;                    // persists for the j=2047 tail store
#pragma unroll
  for (int q = 0; q < 8; ++q) {
    const int j4 = lane + 64 * q;                  // wave instr covers 1KB contiguous
    const float4 vv = rowp[j4];
    const int jb = j4 * 4;
    const float vs[4] = {vv.x, vv.y, vv.z, vv.w};
    float qh[4], qf[4];
#pragma unroll
    for (int u = 0; u < 4; ++u) {
      const int j = jb + u;
      const float L = vs[u] - rm;                  // identical fp32 value as gemm epilogue
      const bool offd = (j != i);
      const bool same = (slab[j] == li);
      const bool hnm  = offd && !same && (L >= thr);
      const bool fin  = offd && (same || hnm);
      if (offd) se += __expf(L);
      if (fin)  { sp += L; ++pc; }
      qh[u] = hnm ? 1.0f : 0.0f;
      qf[u] = fin ? 1.0f : 0.0f;
    }
    float uph = __shfl_up(qh[3], 1, 64);           // lane L <- lane L-1 's .w
    float upf = __shfl_up(qf[3], 1, 64);
    if (lane == 0) { uph = carry_h; upf = carry_f; }
    if (q == 0 && lane == 0) {
      // row head: j = 0,1,2 (j=-1 does not exist); scalar dwords
      ohnm[rowb + 0] = qh[0]; ohnm[rowb + 1] = qh[1]; ohnm[rowb + 2] = qh[2];
      ofin[rowb + 0] = qf[0]; ofin[rowb + 1] = qf[1]; ofin[rowb + 2] = qf[2];
    } else {
      const float4 sh = {uph, qh[0], qh[1], qh[2]};
      const float4 sf = {upf, qf[0], qf[1], qf[2]};
      *(float4*)&ohnm[rowb + jb - 1] = sh;         // byte = 4*(2048i+jb) == 0 mod 16: aligned
      *(float4*)&ofin[rowb + jb - 1] = sf;
    }
    carry_h = __shfl(qh[3], 63, 64);               // chunk carry: j = 256q+255
    carry_f = __shfl(qf[3], 63, 64);
    qh3 = qh[3]; qf3 = qf[3];
  }
  if (lane == 63) {                                // row tail: j = 2047
    ohnm[rowb + 2047] = qh3;
    ofin[rowb + 2047] = qf3;
  }
  float pcf = (float)pc;
#pragma unroll
  for (int o = 32; o > 0; o >>= 1) {               // wave-only reduction, no barriers
    se  += __shfl_down(se,  o, 64);
    sp  += __shfl_down(sp,  o, 64);
    pcf += __shfl_down(pcf, o, 64);
  }
  if (lane == 0) {
    const double P = (double)pcf;
    const bool single = (P == 0.0);
    const double mlpp = ((double)sp - P * log((double)se + 1e-12)) / (P + (single ? 1.0 : 0.0));
    lsum[w]  = single ? 0.0 : -mlpp;
    sflag[w] = single ? 1u : 0u;
  }
  __syncthreads();
  if (t == 0) {
    agent_store_f64(&lsum_g[blockIdx.x], lsum[0] + lsum[1] + lsum[2] + lsum[3]);
    agent_store_u32(&scnt_g[blockIdx.x], sflag[0] + sflag[1] + sflag[2] + sflag[3]);
    asm volatile("s_waitcnt vmcnt(0)" ::: "memory");  // drain sc-stores; NO L2 flush
    const int sl = (int)(blockIdx.x & 7);
    unsigned am = 0u;
    if (atomicAdd(&c->sing8[sl * 16], 1u) == 63u)     // 512 blocks / 8 slices = 64 each
      am = (atomicAdd(&c->singles, 1u) == 7u) ? 1u : 0u;
    amlast = am;
  }
  __syncthreads();
  if (!amlast) return;

  // ---- finalize tail: reduce 512 partials (plain first-touch loads; writers were sc-stores) ----
  double ls = lsum_g[t] + lsum_g[t + 256];
  unsigned sc = scnt_g[t] + scnt_g[t + 256];
#pragma unroll
  for (int o = 32; o > 0; o >>= 1) {
    ls += __shfl_down(ls, o, 64);
    sc += __shfl_down(sc, o, 64);
  }
  if (lane == 0) { lsum[w] = ls; sflag[w] = sc; }  // reuse shared arrays (slots 0..3)
  __syncthreads();
  if (t == 0) {
    const double tot = lsum[0] + lsum[1] + lsum[2] + lsum[3];
    const unsigned sg = sflag[0] + sflag[1] + sflag[2] + sflag[3];
    out[0] = (float)(tot / ((double)Bn - (double)sg));
  }
}

// ---------------- launch: 3 dispatches ----------------
extern "C" void kernel_launch(void* const* d_in, const int* in_sizes, int n_in,
                              void* d_out, int out_size, void* d_ws, size_t ws_size,
                              hipStream_t stream) {
  const float* F      = (const float*)d_in[0];
  const int*   labels = (const int*)d_in[1];
  float* out = (float*)d_out;

  char* ws = (char*)d_ws;
  Ctl*      c      = (Ctl*)ws;                              // ~132 KB
  float*    rm     = (float*)(ws + 786432);                 // 768 KB offset, 8 KB
  double*   lsum_g = (double*)(ws + 802816);                // 512 doubles, 4 KB
  unsigned* scnt_g = (unsigned*)(ws + 806912);              // 512 uints, 2 KB
  float*    adc    = (float*)(ws + (1u << 20));             // 1 MiB offset, 16.78 MB

  rowdot_k<<<32, 64, 0, stream>>>(F, rm, c);                // self-dots + Ctl zeroing
  gemm_adc<<<528, 256, 0, stream>>>(F, rm, labels, adc, c); // BK=32 tiles + select tail
  final_k<<<512, 256, 0, stream>>>(adc, labels, c, out, lsum_g, scnt_g); // aligned-store masks+loss
}